// Round 2
// baseline (418.772 us; speedup 1.0000x reference)
//
#include <hip/hip_runtime.h>

// g[b,h,w] = (1/N) * sum_n conj(H[n]) * (H[n]*x[b] - y[b,n])
//          = x[b]*(1/N)*sum_n |H[n]|^2  -  (1/N)*sum_n conj(H[n])*y[b,n]
//
// Round 7: two clean levers, no LDS.
//  (1) one thread per COMPLEX (float2) -> 262144 threads = 4096 waves =
//      4 waves/SIMD, with NO cross-wave reduction / barrier / idle lanes
//      (R6's occupancy without R6's baggage). ~110 VGPR, capped 128.
//  (2) H loads are NOT nontemporal: Hreal is 134 MB < 256 MB Infinity
//      Cache and persists across bench iterations (fills only poison the
//      output/workspace). NT on H was discarding a guaranteed L3 hit.
//      y stays NT (268 MB streaming, prefer-evict, won't wash H out).
//  Pipeline: groups of 8 n's, next group's 24 loads (12 KB/wave) issued
//  before current group's FMAs -> 192 KB/CU in flight at 4 waves/SIMD.

typedef float f2 __attribute__((ext_vector_type(2)));

#define ACCUM2(h, v0, v1)                          \
    do {                                           \
        s   += (h).x * (h).x + (h).y * (h).y;      \
        a0r += (h).x * (v0).x + (h).y * (v0).y;    \
        a0i += (h).x * (v0).y - (h).y * (v0).x;    \
        a1r += (h).x * (v1).x + (h).y * (v1).y;    \
        a1i += (h).x * (v1).y - (h).y * (v1).x;    \
    } while (0)

__global__ void __launch_bounds__(256, 4) idt_fused_kernel(
    const f2* __restrict__ H2,   // [N][Q]
    const f2* __restrict__ Y2,   // [B=2][N][Q]
    const f2* __restrict__ X2,   // [B=2][Q]
    f2* __restrict__ O2,         // [B=2][Q]
    const int* __restrict__ nbf,
    int N, int Q)
{
    const int q = blockIdx.x * blockDim.x + threadIdx.x;
    if (q >= Q) return;

    float s = 0.f;
    float a0r = 0.f, a0i = 0.f;   // b=0: sum conj(H)*y0
    float a1r = 0.f, a1i = 0.f;   // b=1: sum conj(H)*y1

    const f2* hp = H2 + q;
    const f2* y0 = Y2 + q;                    // b=0
    const f2* y1 = Y2 + (size_t)N * Q + q;    // b=1

    const int G = N >> 3;                     // groups of 8 n's => 8

    f2 cH[8], c0[8], c1[8];
    #pragma unroll
    for (int j = 0; j < 8; ++j) {
        cH[j] = hp[(size_t)j * Q];            // regular load: keep H in L3
        c0[j] = __builtin_nontemporal_load(y0 + (size_t)j * Q);
        c1[j] = __builtin_nontemporal_load(y1 + (size_t)j * Q);
    }

    for (int g = 0; g < G - 1; ++g) {
        const size_t base = (size_t)(g + 1) * 8 * Q;

        // issue next group's loads first (stay outstanding through compute)
        f2 nH[8], n0[8], n1[8];
        #pragma unroll
        for (int j = 0; j < 8; ++j) {
            nH[j] = hp[base + (size_t)j * Q];
            n0[j] = __builtin_nontemporal_load(y0 + base + (size_t)j * Q);
            n1[j] = __builtin_nontemporal_load(y1 + base + (size_t)j * Q);
        }

        #pragma unroll
        for (int j = 0; j < 8; ++j) ACCUM2(cH[j], c0[j], c1[j]);

        #pragma unroll
        for (int j = 0; j < 8; ++j) { cH[j] = nH[j]; c0[j] = n0[j]; c1[j] = n1[j]; }
    }

    #pragma unroll
    for (int j = 0; j < 8; ++j) ACCUM2(cH[j], c0[j], c1[j]);

    const float inv = 1.0f / (float)nbf[0];

    f2 x0 = X2[q];
    f2 x1 = X2[(size_t)Q + q];

    f2 o0, o1;
    o0.x = (x0.x * s - a0r) * inv;
    o0.y = (x0.y * s - a0i) * inv;
    o1.x = (x1.x * s - a1r) * inv;
    o1.y = (x1.y * s - a1i) * inv;

    __builtin_nontemporal_store(o0, O2 + q);
    __builtin_nontemporal_store(o1, O2 + (size_t)Q + q);
}

extern "C" void kernel_launch(void* const* d_in, const int* in_sizes, int n_in,
                              void* d_out, int out_size, void* d_ws, size_t ws_size,
                              hipStream_t stream) {
    const float* f_ipt = (const float*)d_in[0];   // [B,H,W,2]
    const float* f_y   = (const float*)d_in[1];   // [B,N,H,W,2]
    const float* Hreal = (const float*)d_in[2];   // [N,H,W,2]
    const int*   nbf   = (const int*)d_in[3];     // scalar NBFkeep

    const int B = in_sizes[1] / in_sizes[2];      // = 2
    const int N = in_sizes[1] / in_sizes[0];      // = 64
    const int Q = in_sizes[0] / B / 2;            // = 262144 complex per batch

    dim3 block(256);
    dim3 grid((Q + block.x - 1) / block.x);       // 1024 blocks
    idt_fused_kernel<<<grid, block, 0, stream>>>(
        (const f2*)Hreal, (const f2*)f_y, (const f2*)f_ipt,
        (f2*)d_out, nbf, N, Q);
}

// Round 3
// 408.682 us; speedup vs baseline: 1.0247x; 1.0247x over previous
//
#include <hip/hip_runtime.h>

// g[b,h,w] = (1/N) * sum_n conj(H[n]) * (H[n]*x[b] - y[b,n])
//          = x[b]*(1/N)*sum_n |H[n]|^2  -  (1/N)*sum_n conj(H[n])*y[b,n]
//
// Round 8: revert to R5 geometry (best: 406.7 us; float4, 256-thr blocks,
// 512 blocks = 2 waves/SIMD, all-NT) -- R6/R7 occupancy probes both
// regressed, occupancy is not the limiter. One micro-fix on top of R5:
// depth-2 double-buffer with unroll-by-2 and NO register rotation copies.
// R5's nH->cH copies forced vmcnt(0) (full drain, outstanding->0 once per
// group); here the compiler can wait vmcnt(12), keeping the next group's
// 12 loads (12 KB/wave) in flight while the current group is consumed.
// Same traffic, same instruction count; worst case ties R5.

typedef float f4 __attribute__((ext_vector_type(4)));

#define ACCUM(hv, v0, v1)                                   \
    do {                                                    \
        s0 += (hv).x * (hv).x + (hv).y * (hv).y;            \
        s1 += (hv).z * (hv).z + (hv).w * (hv).w;            \
        a00r += (hv).x * (v0).x + (hv).y * (v0).y;          \
        a00i += (hv).x * (v0).y - (hv).y * (v0).x;          \
        a01r += (hv).z * (v0).z + (hv).w * (v0).w;          \
        a01i += (hv).z * (v0).w - (hv).w * (v0).z;          \
        a10r += (hv).x * (v1).x + (hv).y * (v1).y;          \
        a10i += (hv).x * (v1).y - (hv).y * (v1).x;          \
        a11r += (hv).z * (v1).z + (hv).w * (v1).w;          \
        a11i += (hv).z * (v1).w - (hv).w * (v1).z;          \
    } while (0)

#define LOADG(bufH, buf0, buf1, g)                                            \
    do {                                                                      \
        const size_t base_ = (size_t)(g) * 4 * P;                             \
        _Pragma("unroll")                                                     \
        for (int j = 0; j < 4; ++j) {                                         \
            bufH[j] = __builtin_nontemporal_load(hp + base_ + (size_t)j * P); \
            buf0[j] = __builtin_nontemporal_load(y0 + base_ + (size_t)j * P); \
            buf1[j] = __builtin_nontemporal_load(y1 + base_ + (size_t)j * P); \
        }                                                                     \
    } while (0)

__global__ void __launch_bounds__(256, 2) idt_fused_kernel(
    const f4* __restrict__ H4,   // [N][P]
    const f4* __restrict__ Y4,   // [B=2][N][P]
    const f4* __restrict__ X4,   // [B=2][P]
    f4* __restrict__ O4,         // [B=2][P]
    const int* __restrict__ nbf,
    int N, int P)
{
    int p = blockIdx.x * blockDim.x + threadIdx.x;
    if (p >= P) return;

    float s0 = 0.f, s1 = 0.f;
    float a00r = 0.f, a00i = 0.f, a01r = 0.f, a01i = 0.f;  // b=0
    float a10r = 0.f, a10i = 0.f, a11r = 0.f, a11i = 0.f;  // b=1

    const f4* hp = H4 + p;
    const f4* y0 = Y4 + p;                       // b=0
    const f4* y1 = Y4 + (size_t)N * P + p;       // b=1

    const int G = N >> 2;                        // 16 groups of 4 n's

    f4 aH[4], a0[4], a1[4];                      // buffer A
    f4 bH[4], b0[4], b1[4];                      // buffer B

    LOADG(aH, a0, a1, 0);
    LOADG(bH, b0, b1, 1);

    // G is even (16). Unrolled-by-2 depth-2 pipeline, no register copies:
    // consuming A only needs vmcnt(12) -> B's 12 loads stay in flight.
    for (int g = 0; g < G - 2; g += 2) {
        #pragma unroll
        for (int j = 0; j < 4; ++j) ACCUM(aH[j], a0[j], a1[j]);
        LOADG(aH, a0, a1, g + 2);

        #pragma unroll
        for (int j = 0; j < 4; ++j) ACCUM(bH[j], b0[j], b1[j]);
        LOADG(bH, b0, b1, g + 3);
    }

    #pragma unroll
    for (int j = 0; j < 4; ++j) ACCUM(aH[j], a0[j], a1[j]);
    #pragma unroll
    for (int j = 0; j < 4; ++j) ACCUM(bH[j], b0[j], b1[j]);

    float inv = 1.0f / (float)nbf[0];

    f4 x0 = X4[p];
    f4 x1 = X4[(size_t)P + p];

    f4 o0, o1;
    o0.x = (x0.x * s0 - a00r) * inv;
    o0.y = (x0.y * s0 - a00i) * inv;
    o0.z = (x0.z * s1 - a01r) * inv;
    o0.w = (x0.w * s1 - a01i) * inv;

    o1.x = (x1.x * s0 - a10r) * inv;
    o1.y = (x1.y * s0 - a10i) * inv;
    o1.z = (x1.z * s1 - a11r) * inv;
    o1.w = (x1.w * s1 - a11i) * inv;

    __builtin_nontemporal_store(o0, O4 + p);
    __builtin_nontemporal_store(o1, O4 + (size_t)P + p);
}

extern "C" void kernel_launch(void* const* d_in, const int* in_sizes, int n_in,
                              void* d_out, int out_size, void* d_ws, size_t ws_size,
                              hipStream_t stream) {
    const float* f_ipt = (const float*)d_in[0];   // [B,H,W,2]
    const float* f_y   = (const float*)d_in[1];   // [B,N,H,W,2]
    const float* Hreal = (const float*)d_in[2];   // [N,H,W,2]
    const int*   nbf   = (const int*)d_in[3];     // scalar NBFkeep

    const int B = in_sizes[1] / in_sizes[2];      // = 2
    const int N = in_sizes[1] / in_sizes[0];      // = 64
    const int P = in_sizes[0] / B / 4;            // = 131072 float4 groups per batch

    dim3 block(256);
    dim3 grid((P + block.x - 1) / block.x);       // 512 blocks
    idt_fused_kernel<<<grid, block, 0, stream>>>(
        (const f4*)Hreal, (const f4*)f_y, (const f4*)f_ipt,
        (f4*)d_out, nbf, N, P);
}